// Round 1
// baseline (369.915 us; speedup 1.0000x reference)
//
#include <hip/hip_runtime.h>
#include <math.h>

// Problem constants (fixed by reference setup_inputs)
#define BSZ 4096   // B
#define NROW 8192  // N = 2B
#define DIM 128    // D
#define TAU_INV 10.0f

// ws layout (in floats):
//   pn     [0, N*D)            normalized rows (4 MB)
//   g      [N*D, +256)         label-sum vectors g0,g1
//   cnt    [N*D+256, +2)       label counts in y2 (as float)
//   spart  [N*D+512, +8*N)     per-colchunk partial exp-sums
//   part   [.., +32)           per-block loss partials
#define G_OFF     (NROW * DIM)
#define CNT_OFF   (G_OFF + 256)
#define SPART_OFF (G_OFF + 512)
#define PART_OFF  (SPART_OFF + 8 * NROW)
// total ~4.3 MB of workspace

// ---------------- Kernel 1: row normalization (wave per row) ---------------
__global__ void k_norm(const float* __restrict__ zi, const float* __restrict__ zj,
                       float* __restrict__ pn) {
    int tid  = threadIdx.x;
    int wave = tid >> 6, lane = tid & 63;
    int row  = blockIdx.x * 4 + wave;
    const float* src = (row < BSZ) ? (zi + (size_t)row * DIM)
                                   : (zj + (size_t)(row - BSZ) * DIM);
    float2 v = ((const float2*)src)[lane];
    float ss = v.x * v.x + v.y * v.y;
    #pragma unroll
    for (int m = 32; m; m >>= 1) ss += __shfl_xor(ss, m, 64);
    float nrm = fmaxf(sqrtf(ss), 1e-8f);
    float inv = 1.0f / nrm;
    float2 o; o.x = v.x * inv; o.y = v.y * inv;
    ((float2*)(pn + (size_t)row * DIM))[lane] = o;
}

// ------- Kernel 2: label-sum vectors g0/g1 (one block per d) + counts ------
__global__ void k_colsum(const float* __restrict__ pn, const int* __restrict__ y,
                         float* __restrict__ g, float* __restrict__ cnt) {
    __shared__ float r0[256], r1[256];
    int tid = threadIdx.x;
    if (blockIdx.x < DIM) {
        int d = blockIdx.x;
        float s0 = 0.f, s1 = 0.f;
        for (int r = tid; r < NROW; r += 256) {
            int lab = y[r & (BSZ - 1)];          // y2[r] = y[r % B]
            float v = pn[(size_t)r * DIM + d];
            if (lab) s1 += v; else s0 += v;
        }
        r0[tid] = s0; r1[tid] = s1;
        __syncthreads();
        for (int s = 128; s; s >>= 1) {
            if (tid < s) { r0[tid] += r0[tid + s]; r1[tid] += r1[tid + s]; }
            __syncthreads();
        }
        if (tid == 0) { g[d] = r0[0]; g[DIM + d] = r1[0]; }
    } else {
        float c = 0.f;
        for (int r = tid; r < BSZ; r += 256) c += (float)y[r];
        r0[tid] = c;
        __syncthreads();
        for (int s = 128; s; s >>= 1) {
            if (tid < s) r0[tid] += r0[tid + s];
            __syncthreads();
        }
        if (tid == 0) { cnt[1] = 2.0f * r0[0]; cnt[0] = (float)NROW - 2.0f * r0[0]; }
    }
}

// ---- Kernel 3: fused tiled "SGEMM" + exp + row-sum (the O(N^2 D) part) ----
// grid (64 row-tiles, 8 col-chunks), block 256. Tile 128x128, micro 8x8.
// Rows/cols per thread are STRIDED (tr+16r / tc+16c): with LDS stride 36
// floats, a-reads hit distinct banks (4tr+k), b-reads 2-way alias (free).
#define KC 32
#define LDA 36
__global__ __launch_bounds__(256, 3)
void k_expsum(const float* __restrict__ pn, float* __restrict__ spart) {
    __shared__ float at[128][LDA];
    __shared__ float bt[128][LDA];
    __shared__ float rs[16][128];
    int tid = threadIdx.x;
    int tc = tid & 15, tr = tid >> 4;
    int rowBase  = blockIdx.x * 128;
    int colChunk = blockIdx.y;            // 0..7, 1024 cols each

    int ld_row  = tid >> 3;               // 0..31
    int ld_quad = (tid & 7) * 4;          // 0,4,...,28

    float rowsum[8];
    #pragma unroll
    for (int r = 0; r < 8; ++r) rowsum[r] = 0.f;

    for (int s = 0; s < 8; ++s) {
        int colBase = colChunk * 1024 + s * 128;
        float acc[8][8];
        #pragma unroll
        for (int r = 0; r < 8; ++r)
            #pragma unroll
            for (int c = 0; c < 8; ++c) acc[r][c] = 0.f;

        for (int kc = 0; kc < DIM; kc += KC) {
            __syncthreads();   // previous tile's reads done before restage
            #pragma unroll
            for (int i = 0; i < 4; ++i) {
                int rr = ld_row + 32 * i;
                float4 va = *(const float4*)(pn + (size_t)(rowBase + rr) * DIM + kc + ld_quad);
                *(float4*)(&at[rr][ld_quad]) = va;
                float4 vb = *(const float4*)(pn + (size_t)(colBase + rr) * DIM + kc + ld_quad);
                *(float4*)(&bt[rr][ld_quad]) = vb;
            }
            __syncthreads();
            #pragma unroll
            for (int k = 0; k < KC; k += 4) {
                float4 a4[8], b4[8];
                #pragma unroll
                for (int r = 0; r < 8; ++r) a4[r] = *(const float4*)(&at[tr + 16 * r][k]);
                #pragma unroll
                for (int c = 0; c < 8; ++c) b4[c] = *(const float4*)(&bt[tc + 16 * c][k]);
                #pragma unroll
                for (int r = 0; r < 8; ++r)
                    #pragma unroll
                    for (int c = 0; c < 8; ++c) {
                        acc[r][c] = fmaf(a4[r].x, b4[c].x, acc[r][c]);
                        acc[r][c] = fmaf(a4[r].y, b4[c].y, acc[r][c]);
                        acc[r][c] = fmaf(a4[r].z, b4[c].z, acc[r][c]);
                        acc[r][c] = fmaf(a4[r].w, b4[c].w, acc[r][c]);
                    }
            }
        }
        // exp + accumulate row sums, excluding the diagonal exactly
        #pragma unroll
        for (int r = 0; r < 8; ++r) {
            int row = rowBase + tr + 16 * r;
            #pragma unroll
            for (int c = 0; c < 8; ++c) {
                int col = colBase + tc + 16 * c;
                if (row != col) rowsum[r] += expf(acc[r][c] * TAU_INV);
            }
        }
    }
    // reduce the 16 tc-partials per row, write partial S for this col chunk
    #pragma unroll
    for (int r = 0; r < 8; ++r) rs[tc][tr + 16 * r] = rowsum[r];
    __syncthreads();
    if (tid < 128) {
        float s = 0.f;
        #pragma unroll
        for (int t = 0; t < 16; ++t) s += rs[t][tid];
        spart[(size_t)colChunk * NROW + rowBase + tid] = s;
    }
}

// --------------- Kernel 4: per-row finalize + block reduction --------------
__global__ void k_finalize(const float* __restrict__ pn, const float* __restrict__ spart,
                           const float* __restrict__ g, const float* __restrict__ cnt,
                           const int* __restrict__ y, float* __restrict__ partial) {
    __shared__ float red[256];
    int row = blockIdx.x * 256 + threadIdx.x;
    float S = 0.f;
    #pragma unroll
    for (int ch = 0; ch < 8; ++ch) S += spart[(size_t)ch * NROW + row];
    int lab = y[row & (BSZ - 1)];
    float C = cnt[lab] - 1.0f;               // pos count excludes self
    const float* pr = pn + (size_t)row * DIM;
    const float* gl = g + lab * DIM;
    float dg = 0.f, dself = 0.f;
    #pragma unroll
    for (int d = 0; d < DIM; d += 4) {
        float4 p4 = *(const float4*)(pr + d);
        float4 g4 = *(const float4*)(gl + d);
        dg    += p4.x * g4.x + p4.y * g4.y + p4.z * g4.z + p4.w * g4.w;
        dself += p4.x * p4.x + p4.y * p4.y + p4.z * p4.z + p4.w * p4.w;
    }
    float P = (dg - dself) * TAU_INV;        // sum of sims over positives (no self)
    float contrib = logf(S) - P / C;         // -(mean_log_prob_pos)
    red[threadIdx.x] = contrib;
    __syncthreads();
    for (int s = 128; s; s >>= 1) {
        if (threadIdx.x < s) red[threadIdx.x] += red[threadIdx.x + s];
        __syncthreads();
    }
    if (threadIdx.x == 0) partial[blockIdx.x] = red[0];
}

// --------------------- Kernel 5: final 32-wide reduce ----------------------
__global__ void k_sum(const float* __restrict__ partial, float* __restrict__ out) {
    float v = (threadIdx.x < 32) ? partial[threadIdx.x] : 0.f;
    #pragma unroll
    for (int m = 32; m; m >>= 1) v += __shfl_xor(v, m, 64);
    if (threadIdx.x == 0) out[0] = v;
}

extern "C" void kernel_launch(void* const* d_in, const int* in_sizes, int n_in,
                              void* d_out, int out_size, void* d_ws, size_t ws_size,
                              hipStream_t stream) {
    const float* zi = (const float*)d_in[0];
    const float* zj = (const float*)d_in[1];
    const int*   y  = (const int*)d_in[2];
    float* out = (float*)d_out;
    float* ws  = (float*)d_ws;

    float* pn      = ws;
    float* g       = ws + G_OFF;
    float* cnt     = ws + CNT_OFF;
    float* spart   = ws + SPART_OFF;
    float* partial = ws + PART_OFF;

    k_norm<<<NROW / 4, 256, 0, stream>>>(zi, zj, pn);
    k_colsum<<<DIM + 1, 256, 0, stream>>>(pn, y, g, cnt);
    k_expsum<<<dim3(NROW / 128, 8), 256, 0, stream>>>(pn, spart);
    k_finalize<<<NROW / 256, 256, 0, stream>>>(pn, spart, g, cnt, y, partial);
    k_sum<<<1, 64, 0, stream>>>(partial, out);
}

// Round 3
// 115.784 us; speedup vs baseline: 3.1949x; 3.1949x over previous
//
#include <hip/hip_runtime.h>
#include <math.h>

// Problem constants (fixed by reference setup_inputs)
#define BSZ 4096   // B
#define NROW 8192  // N = 2B
#define DIM 128    // D
#define LOG2E10 14.426950408889634f   // 10 / ln(2): exp(10x) = exp2(x * this)

typedef __attribute__((ext_vector_type(8))) short bf16x8;   // 8 bf16 = 4 VGPRs
typedef __attribute__((ext_vector_type(4))) float f32x4;    // MFMA acc

// ws layout (in floats):
//   pnh    [0, N*D/2)        normalized rows as bf16 (N*D ushorts = 2 MB)
//   g      [+256)            label-sum vectors g0,g1 (fp32)
//   cnt    [+2)              label counts in y2
//   spart  [+16*N)           per-(colchunk,wc) partial exp row-sums (16 slices)
//   part   [+32)             per-block loss partials
#define PNH_F     (NROW * DIM / 2)
#define G_OFF     PNH_F
#define CNT_OFF   (G_OFF + 256)
#define SPART_OFF (G_OFF + 512)
#define PART_OFF  (SPART_OFF + 16 * NROW)

__device__ __forceinline__ float bf2f(unsigned short h) {
    return __uint_as_float(((unsigned)h) << 16);
}
__device__ __forceinline__ unsigned short f2bf(float f) {  // RNE
    unsigned u = __float_as_uint(f);
    return (unsigned short)((u + 0x7FFF + ((u >> 16) & 1)) >> 16);
}

// ---------------- Kernel 1: row normalization -> bf16 (wave per row) -------
__global__ void k_norm(const float* __restrict__ zi, const float* __restrict__ zj,
                       unsigned short* __restrict__ pnh) {
    int tid  = threadIdx.x;
    int wave = tid >> 6, lane = tid & 63;
    int row  = blockIdx.x * 4 + wave;
    const float* src = (row < BSZ) ? (zi + (size_t)row * DIM)
                                   : (zj + (size_t)(row - BSZ) * DIM);
    float2 v = ((const float2*)src)[lane];
    float ss = v.x * v.x + v.y * v.y;
    #pragma unroll
    for (int m = 32; m; m >>= 1) ss += __shfl_xor(ss, m, 64);
    float inv = 1.0f / fmaxf(sqrtf(ss), 1e-8f);
    unsigned short h0 = f2bf(v.x * inv), h1 = f2bf(v.y * inv);
    ((unsigned*)(pnh + (size_t)row * DIM))[lane] = (unsigned)h0 | ((unsigned)h1 << 16);
}

// ------- Kernel 2: label-sum vectors g0/g1 (one block per d) + counts ------
__global__ void k_colsum(const unsigned short* __restrict__ pnh, const int* __restrict__ y,
                         float* __restrict__ g, float* __restrict__ cnt) {
    __shared__ float r0[256], r1[256];
    int tid = threadIdx.x;
    if (blockIdx.x < DIM) {
        int d = blockIdx.x;
        float s0 = 0.f, s1 = 0.f;
        for (int r = tid; r < NROW; r += 256) {
            int lab = y[r & (BSZ - 1)];          // y2[r] = y[r % B]
            float v = bf2f(pnh[(size_t)r * DIM + d]);
            if (lab) s1 += v; else s0 += v;
        }
        r0[tid] = s0; r1[tid] = s1;
        __syncthreads();
        for (int s = 128; s; s >>= 1) {
            if (tid < s) { r0[tid] += r0[tid + s]; r1[tid] += r1[tid + s]; }
            __syncthreads();
        }
        if (tid == 0) { g[d] = r0[0]; g[DIM + d] = r1[0]; }
    } else {
        float c = 0.f;
        for (int r = tid; r < BSZ; r += 256) c += (float)y[r];
        r0[tid] = c;
        __syncthreads();
        for (int s = 128; s; s >>= 1) {
            if (tid < s) r0[tid] += r0[tid + s];
            __syncthreads();
        }
        if (tid == 0) { cnt[1] = 2.0f * r0[0]; cnt[0] = (float)NROW - 2.0f * r0[0]; }
    }
}

// ---- Kernel 3: bf16 MFMA GEMM + exp + row-sum (the O(N^2 D) part) --------
// Block = 256 thr (4 waves, 2x2), output tile 128 rows x 1024 cols (8 s-subtiles).
// A-frags: direct global->VGPR, held for whole kernel (K=128 = 4 ksteps).
// B tile: LDS double-buffer 2x32KB, XOR-swizzled (j ^= row&15) -> 2-way banks only.
// spart is split by (chunk, wc): the two wc waves cover different 64-col
// halves and MUST NOT alias (round-2 bug: they overwrote each other -> S/2).
__global__ __launch_bounds__(256, 2)
void k_expsum(const unsigned short* __restrict__ pnh, float* __restrict__ spart) {
    __shared__ short bt[2][128 * 128];
    int tid  = threadIdx.x;
    int lane = tid & 63;
    int wave = tid >> 6;
    int wr = wave & 1, wc = wave >> 1;
    int l15 = lane & 15, q = lane >> 4;
    int rowBase = blockIdx.x * 128;
    int chunk   = blockIdx.y;            // 0..7 -> cols [chunk*1024, +1024)

    // ---- A fragments from global (16 frags = 64 VGPRs) ----
    // A-layout: lane holds A[m = lane&15][k = q*8 + j], frag k-window = ks*32
    bf16x8 a[4][4];
    const unsigned short* abase = pnh + (size_t)(rowBase + wr * 64 + l15) * DIM + q * 8;
    #pragma unroll
    for (int r = 0; r < 4; ++r)
        #pragma unroll
        for (int ks = 0; ks < 4; ++ks)
            a[r][ks] = *(const bf16x8*)(abase + (size_t)r * 16 * DIM + ks * 32);

    float rs[4][4];
    #pragma unroll
    for (int r = 0; r < 4; ++r)
        #pragma unroll
        for (int e = 0; e < 4; ++e) rs[r][e] = 0.f;

    // ---- staging: 32KB B tile, coalesced global, swizzled LDS write ----
    auto stage = [&](int s, int b) {
        const float4* src = (const float4*)(pnh + (size_t)(chunk * 1024 + s * 128) * DIM);
        #pragma unroll
        for (int i = 0; i < 8; ++i) {
            int idx = tid + 256 * i;       // 16B chunk index
            int row = idx >> 4, j = idx & 15;
            float4 v = src[idx];
            *(float4*)(&bt[b][row * 128 + ((j ^ (row & 15)) << 3)]) = v;
        }
    };

    stage(0, 0);
    __syncthreads();

    for (int s = 0; s < 8; ++s) {
        int cur = s & 1;
        if (s < 7) stage(s + 1, cur ^ 1);   // prefetch next tile into other buffer

        f32x4 acc[4][4];
        #pragma unroll
        for (int r = 0; r < 4; ++r)
            #pragma unroll
            for (int c = 0; c < 4; ++c) acc[r][c] = (f32x4){0.f, 0.f, 0.f, 0.f};

        const short* buf = bt[cur];
        #pragma unroll
        for (int ks = 0; ks < 4; ++ks)
            #pragma unroll
            for (int c = 0; c < 4; ++c) {
                int bcol = wc * 64 + c * 16 + l15;   // bcol&15 == l15
                bf16x8 bfrag = *(const bf16x8*)(buf + bcol * 128 + (((ks * 4 + q) ^ l15) << 3));
                #pragma unroll
                for (int r = 0; r < 4; ++r)
                    acc[r][c] = __builtin_amdgcn_mfma_f32_16x16x32_bf16(a[r][ks], bfrag, acc[r][c], 0, 0, 0);
            }

        // epilogue: exp(10*sim), mask exact diagonal, accumulate row sums in regs
        int colBase = chunk * 1024 + s * 128;
        bool diagBlk = (rowBase == colBase);
        #pragma unroll
        for (int r = 0; r < 4; ++r)
            #pragma unroll
            for (int c = 0; c < 4; ++c) {
                int cl = wc * 64 + c * 16 + l15;
                #pragma unroll
                for (int e = 0; e < 4; ++e) {
                    int rl = wr * 64 + r * 16 + q * 4 + e;   // C-layout: row=q*4+reg
                    float ex = exp2f(acc[r][c][e] * LOG2E10);
                    if (diagBlk && rl == cl) ex = 0.f;
                    rs[r][e] += ex;
                }
            }
        __syncthreads();   // staging writes done + this tile's reads done
    }

    // reduce over the 16 columns held across lanes 0..15 of each quad-group;
    // each (chunk, wc) pair owns its own spart slice (no cross-wave aliasing)
    #pragma unroll
    for (int r = 0; r < 4; ++r)
        #pragma unroll
        for (int e = 0; e < 4; ++e) {
            float v = rs[r][e];
            v += __shfl_xor(v, 1, 16);
            v += __shfl_xor(v, 2, 16);
            v += __shfl_xor(v, 4, 16);
            v += __shfl_xor(v, 8, 16);
            if (l15 == 0)
                spart[(size_t)(chunk * 2 + wc) * NROW + rowBase + wr * 64 + r * 16 + q * 4 + e] = v;
        }
}

// --------------- Kernel 4: per-row finalize + block reduction --------------
__global__ void k_finalize(const unsigned short* __restrict__ pnh, const float* __restrict__ spart,
                           const float* __restrict__ g, const float* __restrict__ cnt,
                           const int* __restrict__ y, float* __restrict__ partial) {
    __shared__ float red[256];
    int row = blockIdx.x * 256 + threadIdx.x;
    float S = 0.f;
    #pragma unroll
    for (int ch = 0; ch < 16; ++ch) S += spart[(size_t)ch * NROW + row];
    int lab = y[row & (BSZ - 1)];
    float C = cnt[lab] - 1.0f;               // pos count excludes self
    const unsigned short* pr = pnh + (size_t)row * DIM;
    const float* gl = g + lab * DIM;
    float dg = 0.f, dself = 0.f;
    #pragma unroll
    for (int d = 0; d < DIM; d += 8) {
        uint4 u = *(const uint4*)(pr + d);
        float p0 = __uint_as_float(u.x << 16), p1 = __uint_as_float(u.x & 0xFFFF0000u);
        float p2 = __uint_as_float(u.y << 16), p3 = __uint_as_float(u.y & 0xFFFF0000u);
        float p4 = __uint_as_float(u.z << 16), p5 = __uint_as_float(u.z & 0xFFFF0000u);
        float p6 = __uint_as_float(u.w << 16), p7 = __uint_as_float(u.w & 0xFFFF0000u);
        float4 g0 = *(const float4*)(gl + d);
        float4 g1 = *(const float4*)(gl + d + 4);
        dg    += p0 * g0.x + p1 * g0.y + p2 * g0.z + p3 * g0.w
               + p4 * g1.x + p5 * g1.y + p6 * g1.z + p7 * g1.w;
        dself += p0 * p0 + p1 * p1 + p2 * p2 + p3 * p3
               + p4 * p4 + p5 * p5 + p6 * p6 + p7 * p7;
    }
    float P = (dg - dself) * 10.0f;          // sum of sims over positives (no self)
    float contrib = logf(S) - P / C;         // -(mean log prob pos) for this row
    red[threadIdx.x] = contrib;
    __syncthreads();
    for (int s = 128; s; s >>= 1) {
        if (threadIdx.x < s) red[threadIdx.x] += red[threadIdx.x + s];
        __syncthreads();
    }
    if (threadIdx.x == 0) partial[blockIdx.x] = red[0];
}

// --------------------- Kernel 5: final 32-wide reduce ----------------------
__global__ void k_sum(const float* __restrict__ partial, float* __restrict__ out) {
    float v = (threadIdx.x < 32) ? partial[threadIdx.x] : 0.f;
    #pragma unroll
    for (int m = 32; m; m >>= 1) v += __shfl_xor(v, m, 64);
    if (threadIdx.x == 0) out[0] = v;
}

extern "C" void kernel_launch(void* const* d_in, const int* in_sizes, int n_in,
                              void* d_out, int out_size, void* d_ws, size_t ws_size,
                              hipStream_t stream) {
    const float* zi = (const float*)d_in[0];
    const float* zj = (const float*)d_in[1];
    const int*   y  = (const int*)d_in[2];
    float* out = (float*)d_out;
    float* ws  = (float*)d_ws;

    unsigned short* pnh = (unsigned short*)ws;      // N*D bf16
    float* g       = ws + G_OFF;
    float* cnt     = ws + CNT_OFF;
    float* spart   = ws + SPART_OFF;
    float* partial = ws + PART_OFF;

    k_norm<<<NROW / 4, 256, 0, stream>>>(zi, zj, pnh);
    k_colsum<<<DIM + 1, 256, 0, stream>>>(pnh, y, g, cnt);
    k_expsum<<<dim3(NROW / 128, 8), 256, 0, stream>>>(pnh, spart);
    k_finalize<<<NROW / 256, 256, 0, stream>>>(pnh, spart, g, cnt, y, partial);
    k_sum<<<1, 64, 0, stream>>>(partial, out);
}

// Round 4
// 105.120 us; speedup vs baseline: 3.5190x; 1.1014x over previous
//
#include <hip/hip_runtime.h>
#include <math.h>

// Problem constants (fixed by reference setup_inputs)
#define BSZ 4096   // B
#define NROW 8192  // N = 2B
#define DIM 128    // D
#define LOG2E10 14.426950408889634f   // 10 / ln(2): exp(10x) = exp2(x * this)

typedef __attribute__((ext_vector_type(8))) short bf16x8;   // 8 bf16 = 4 VGPRs
typedef __attribute__((ext_vector_type(4))) float f32x4;    // MFMA acc

// ws layout (in floats):
//   pnh    [0, N*D/2)        normalized rows as bf16 (N*D ushorts = 2 MB)
//   g      [+256)            label-sum vectors g0,g1 (fp32, atomically built)
//   cnt    [+2)              label counts in y2
//   spart  [+16*N)           per-colchunk partial exp row-sums (16 slices)
//   part   [+2048)           per-block loss partials
#define PNH_F     (NROW * DIM / 2)
#define G_OFF     PNH_F
#define CNT_OFF   (G_OFF + 256)
#define SPART_OFF (G_OFF + 512)
#define PART_OFF  (SPART_OFF + 16 * NROW)

__device__ __forceinline__ unsigned short f2bf(float f) {  // RNE
    unsigned u = __float_as_uint(f);
    return (unsigned short)((u + 0x7FFF + ((u >> 16) & 1)) >> 16);
}

// ------ Kernel 1: row normalization -> bf16 (wave per row) + zero g -------
__global__ void k_norm(const float* __restrict__ zi, const float* __restrict__ zj,
                       unsigned short* __restrict__ pnh, float* __restrict__ g) {
    int tid  = threadIdx.x;
    if (blockIdx.x == 0) g[tid] = 0.f;      // zero the 256-float g before k_colsum
    int wave = tid >> 6, lane = tid & 63;
    int row  = blockIdx.x * 4 + wave;
    const float* src = (row < BSZ) ? (zi + (size_t)row * DIM)
                                   : (zj + (size_t)(row - BSZ) * DIM);
    float2 v = ((const float2*)src)[lane];
    float ss = v.x * v.x + v.y * v.y;
    #pragma unroll
    for (int m = 32; m; m >>= 1) ss += __shfl_xor(ss, m, 64);
    float inv = 1.0f / fmaxf(sqrtf(ss), 1e-8f);
    unsigned short h0 = f2bf(v.x * inv), h1 = f2bf(v.y * inv);
    ((unsigned*)(pnh + (size_t)row * DIM))[lane] = (unsigned)h0 | ((unsigned)h1 << 16);
}

// ---- Kernel 2: label-sum vectors g0/g1, coalesced row-major + atomics ----
// blocks 0..127: block b sums rows [b*64, +64) into per-label partials,
// atomicAdd into g. block 128: label counts.
__global__ void k_colsum(const unsigned short* __restrict__ pnh, const int* __restrict__ y,
                         float* __restrict__ g, float* __restrict__ cnt) {
    __shared__ float red[4][4][64];   // [rowgrp][{s0a,s0b,s1a,s1b}][d2]
    int tid = threadIdx.x;
    if (blockIdx.x < 128) {
        int d2 = tid & 63;            // uint index: holds d = 2*d2, 2*d2+1
        int rg = tid >> 6;            // 0..3
        int row0 = blockIdx.x * 64 + rg * 16;
        float s0a = 0.f, s0b = 0.f, s1a = 0.f, s1b = 0.f;
        #pragma unroll 4
        for (int i = 0; i < 16; ++i) {
            int r = row0 + i;
            unsigned u = ((const unsigned*)(pnh + (size_t)r * DIM))[d2];
            float va = __uint_as_float(u << 16);
            float vb = __uint_as_float(u & 0xFFFF0000u);
            if (y[r & (BSZ - 1)]) { s1a += va; s1b += vb; }
            else                  { s0a += va; s0b += vb; }
        }
        red[rg][0][d2] = s0a; red[rg][1][d2] = s0b;
        red[rg][2][d2] = s1a; red[rg][3][d2] = s1b;
        __syncthreads();
        int lab = tid >> 7, d = tid & 127;
        int which = lab * 2 + (d & 1), dd2 = d >> 1;
        float s = red[0][which][dd2] + red[1][which][dd2]
                + red[2][which][dd2] + red[3][which][dd2];
        atomicAdd(&g[lab * DIM + d], s);
    } else {
        __shared__ float r0[256];
        float c = 0.f;
        for (int r = tid; r < BSZ; r += 256) c += (float)y[r];
        r0[tid] = c;
        __syncthreads();
        for (int s = 128; s; s >>= 1) {
            if (tid < s) r0[tid] += r0[tid + s];
            __syncthreads();
        }
        if (tid == 0) { cnt[1] = 2.0f * r0[0]; cnt[0] = (float)NROW - 2.0f * r0[0]; }
    }
}

// ---- Kernel 3: bf16 MFMA GEMM + exp + row-sum (the O(N^2 D) part) --------
// grid 64x16 = 1024 blocks = 4 blocks/CU (32KB LDS, <=128 VGPR). Block tile:
// 128 rows x 512 cols (8 subtiles of 64 cols, double-buffered 16KB each).
// Wave w owns rows [w*32, +32): A frags 2x4 in regs, acc 2x4 f32x4.
// XOR swizzle (j ^= row&15): ds_write and ds_read both conflict-free
// (verified round 3: SQ_LDS_BANK_CONFLICT == 0).
__global__ __launch_bounds__(256, 4)
void k_expsum(const unsigned short* __restrict__ pnh, float* __restrict__ spart) {
    __shared__ short bt[2][64 * 128];
    int tid  = threadIdx.x;
    int lane = tid & 63;
    int w    = tid >> 6;
    int l15 = lane & 15, q = lane >> 4;
    int rowBase = blockIdx.x * 128;
    int chunk   = blockIdx.y;            // 0..15 -> cols [chunk*512, +512)
    int rwb     = rowBase + w * 32;      // this wave's first row

    // A fragments: lane holds A[m = l15][k = q*8 + j] per 16x32 k-window
    bf16x8 a[2][4];
    const unsigned short* abase = pnh + (size_t)(rwb + l15) * DIM + q * 8;
    #pragma unroll
    for (int rf = 0; rf < 2; ++rf)
        #pragma unroll
        for (int ks = 0; ks < 4; ++ks)
            a[rf][ks] = *(const bf16x8*)(abase + (size_t)rf * 16 * DIM + ks * 32);

    float rs[2][4];
    #pragma unroll
    for (int rf = 0; rf < 2; ++rf)
        #pragma unroll
        for (int e = 0; e < 4; ++e) rs[rf][e] = 0.f;

    auto stage = [&](int s, int b) {
        const float4* src = (const float4*)(pnh + (size_t)(chunk * 512 + s * 64) * DIM);
        #pragma unroll
        for (int i = 0; i < 4; ++i) {
            int idx = tid + 256 * i;       // 16B chunk index (1024 total)
            int row = idx >> 4, j = idx & 15;
            float4 v = src[idx];
            *(float4*)(&bt[b][row * 128 + ((j ^ (row & 15)) << 3)]) = v;
        }
    };

    stage(0, 0);
    __syncthreads();

    for (int s = 0; s < 8; ++s) {
        int cur = s & 1;
        if (s < 7) stage(s + 1, cur ^ 1);   // prefetch into the other buffer

        f32x4 acc[2][4];
        #pragma unroll
        for (int rf = 0; rf < 2; ++rf)
            #pragma unroll
            for (int c = 0; c < 4; ++c) acc[rf][c] = (f32x4){0.f, 0.f, 0.f, 0.f};

        const short* buf = bt[cur];
        #pragma unroll
        for (int ks = 0; ks < 4; ++ks)
            #pragma unroll
            for (int c = 0; c < 4; ++c) {
                bf16x8 bfrag = *(const bf16x8*)(buf + (c * 16 + l15) * 128 + (((ks * 4 + q) ^ l15) << 3));
                acc[0][c] = __builtin_amdgcn_mfma_f32_16x16x32_bf16(a[0][ks], bfrag, acc[0][c], 0, 0, 0);
                acc[1][c] = __builtin_amdgcn_mfma_f32_16x16x32_bf16(a[1][ks], bfrag, acc[1][c], 0, 0, 0);
            }

        // epilogue: exp(10*sim); diagonal masking only in overlapping waves
        int cb = chunk * 512 + s * 64;
        bool dia = (cb < rwb + 32) && (rwb < cb + 64);   // wave-uniform
        if (dia) {
            #pragma unroll
            for (int rf = 0; rf < 2; ++rf)
                #pragma unroll
                for (int c = 0; c < 4; ++c) {
                    int col = cb + c * 16 + l15;
                    #pragma unroll
                    for (int e = 0; e < 4; ++e) {
                        int row = rwb + rf * 16 + q * 4 + e;   // C-layout row
                        float ex = exp2f(acc[rf][c][e] * LOG2E10);
                        if (row == col) ex = 0.f;
                        rs[rf][e] += ex;
                    }
                }
        } else {
            #pragma unroll
            for (int rf = 0; rf < 2; ++rf)
                #pragma unroll
                for (int c = 0; c < 4; ++c)
                    #pragma unroll
                    for (int e = 0; e < 4; ++e)
                        rs[rf][e] += exp2f(acc[rf][c][e] * LOG2E10);
        }
        __syncthreads();   // this tile's reads done before s+1 restages it
    }

    // reduce over the 16 l15 lanes (columns); waves cover disjoint rows
    #pragma unroll
    for (int rf = 0; rf < 2; ++rf)
        #pragma unroll
        for (int e = 0; e < 4; ++e) {
            float v = rs[rf][e];
            v += __shfl_xor(v, 1, 16);
            v += __shfl_xor(v, 2, 16);
            v += __shfl_xor(v, 4, 16);
            v += __shfl_xor(v, 8, 16);
            if (l15 == 0)
                spart[(size_t)chunk * NROW + rwb + rf * 16 + q * 4 + e] = v;
        }
}

// ------------- Kernel 4: per-row finalize (wave per row, 2048 blocks) ------
__global__ void k_finalize(const unsigned short* __restrict__ pnh, const float* __restrict__ spart,
                           const float* __restrict__ g, const float* __restrict__ cnt,
                           const int* __restrict__ y, float* __restrict__ partial) {
    __shared__ float red[4];
    int tid = threadIdx.x, wv = tid >> 6, lane = tid & 63;
    int row = blockIdx.x * 4 + wv;
    int lab = y[row & (BSZ - 1)];
    unsigned u = ((const unsigned*)(pnh + (size_t)row * DIM))[lane];
    float p0 = __uint_as_float(u << 16);
    float p1 = __uint_as_float(u & 0xFFFF0000u);
    float2 gv = ((const float2*)(g + lab * DIM))[lane];
    float dg = p0 * gv.x + p1 * gv.y;
    float ds = p0 * p0 + p1 * p1;
    float sp = (lane < 16) ? spart[(size_t)lane * NROW + row] : 0.f;
    #pragma unroll
    for (int m = 32; m; m >>= 1) {
        dg += __shfl_xor(dg, m, 64);
        ds += __shfl_xor(ds, m, 64);
        sp += __shfl_xor(sp, m, 64);
    }
    if (lane == 0) {
        float C = cnt[lab] - 1.0f;           // pos count excludes self
        float P = (dg - ds) * 10.0f;         // sum of sims over positives
        red[wv] = logf(sp) - P / C;          // -(mean log prob pos)
    }
    __syncthreads();
    if (tid == 0) partial[blockIdx.x] = red[0] + red[1] + red[2] + red[3];
}

// --------------------- Kernel 5: final reduce of 2048 ----------------------
__global__ void k_sum(const float* __restrict__ partial, float* __restrict__ out) {
    __shared__ float red[256];
    float v = 0.f;
    #pragma unroll
    for (int i = 0; i < 8; ++i) v += partial[threadIdx.x + 256 * i];
    red[threadIdx.x] = v;
    __syncthreads();
    for (int s = 128; s; s >>= 1) {
        if (threadIdx.x < s) red[threadIdx.x] += red[threadIdx.x + s];
        __syncthreads();
    }
    if (threadIdx.x == 0) out[0] = red[0];
}

extern "C" void kernel_launch(void* const* d_in, const int* in_sizes, int n_in,
                              void* d_out, int out_size, void* d_ws, size_t ws_size,
                              hipStream_t stream) {
    const float* zi = (const float*)d_in[0];
    const float* zj = (const float*)d_in[1];
    const int*   y  = (const int*)d_in[2];
    float* out = (float*)d_out;
    float* ws  = (float*)d_ws;

    unsigned short* pnh = (unsigned short*)ws;      // N*D bf16
    float* g       = ws + G_OFF;
    float* cnt     = ws + CNT_OFF;
    float* spart   = ws + SPART_OFF;
    float* partial = ws + PART_OFF;

    k_norm<<<NROW / 4, 256, 0, stream>>>(zi, zj, pnh, g);
    k_colsum<<<129, 256, 0, stream>>>(pnh, y, g, cnt);
    k_expsum<<<dim3(NROW / 128, 16), 256, 0, stream>>>(pnh, spart);
    k_finalize<<<NROW / 4, 256, 0, stream>>>(pnh, spart, g, cnt, y, partial);
    k_sum<<<1, 256, 0, stream>>>(partial, out);
}